// Round 5
// baseline (325.162 us; speedup 1.0000x reference)
//
#include <hip/hip_runtime.h>

// Problem constants (match reference)
#define C_BINS 9
#define H_IN 180
#define W_IN 240
#define IMG 640
#define NEV 250000
#define BATCH 8
#define NEG_SLOPE 0.1f
#define HW (H_IN * W_IN)                         // 43200
#define TN 2048                                  // table intervals (TN+1 nodes over [-1,1])
#define ROWF (W_IN * C_BINS)                     // 2160 floats per accumulated row
#define NROW (2 * BATCH * H_IN)                  // 2880 (b,p,y) rows
#define CAP 512                                  // bucket capacity per row (mean 87)
#define OVF_CAP 4096                             // spill list capacity (expected count: 0)

// workspace layout (bytes)
#define WS_BMAX_OFF   0            // 8 x i32 (float bits; signed-max trick, no init needed)
#define WS_OVFC_OFF   64           // 1 x i32 spill cursor
#define WS_TABLE_OFF  128          // (TN+1) x f32 -> ends 8324
#define WS_CUR_OFF    16384        // NROW x i32, padded x16 (one counter per 64B line)
#define WS_BKT_OFF    262144       // NROW x CAP x float2 = 11.8 MB
#define WS_OVF_OFF    12582912     // OVF_CAP x float4 = 64 KB

// ---------------- kernel A: prep (round-3 structure: table + cursor zero) --
// 2049 independent blocks: block b computes value-table node b; cursor
// zeroing is spread over the grid's first iteration.
__global__ __launch_bounds__(128) void prep_kernel(
        const float* __restrict__ W1, const float* __restrict__ b1,
        const float* __restrict__ W2, const float* __restrict__ b2,
        const float* __restrict__ W3, const float* __restrict__ b3,
        float* __restrict__ table, int* __restrict__ cursor,
        int* __restrict__ ovfc) {
    int blk = blockIdx.x, tid = threadIdx.x;
    int gtid = blk * 128 + tid;
    int gstride = gridDim.x * 128;
    for (int i = gtid; i < NROW * 16; i += gstride) cursor[i] = 0;
    if (gtid == 0) *ovfc = 0;

    // table node `blk`: two LeakyReLU layers + final linear, at s = -1 + 2*blk/TN
    __shared__ float h1s[100];
    __shared__ float red[128];
    float s = -1.f + 2.f * (float)blk / (float)TN;
    if (tid < 100) {
        float h = fmaf(s, W1[tid], b1[tid]);
        h1s[tid] = h > 0.f ? h : NEG_SLOPE * h;
    }
    __syncthreads();
    float acc = 0.f;
    if (tid < 100) {
        #pragma unroll 4
        for (int j = 0; j < 100; ++j) acc = fmaf(h1s[j], W2[j * 100 + tid], acc);
        acc += b2[tid];
        acc = acc > 0.f ? acc : NEG_SLOPE * acc;
        acc *= W3[tid];
    }
    red[tid] = tid < 100 ? acc : 0.f;
    __syncthreads();
    for (int off = 64; off > 0; off >>= 1) {
        if (tid < off) red[tid] += red[tid + off];
        __syncthreads();
    }
    if (tid == 0) table[blk] = red[0] + b3[0];
}

// ---------------- kernel B: place events into row buckets + batch max ------
// One cursor atomic per event (2880 line-padded counters). Payload =
// (raw t, x); b,p,y implied by row. bmax fused (reuses the event read).
// Overflow (pos >= CAP, ~45 sigma out) goes to a tiny spill list that the
// fused kernel scans -- correctness never depends on CAP.
__global__ __launch_bounds__(256) void place_kernel(const float* __restrict__ ev,
                               int* __restrict__ cursor,
                               float2* __restrict__ bucket,
                               int* __restrict__ bmax_i,
                               int* __restrict__ ovfc,
                               float4* __restrict__ ovf) {
    int i = blockIdx.x * 256 + threadIdx.x;
    int tid = threadIdx.x;
    __shared__ int smax[BATCH];
    if (tid < BATCH) smax[tid] = 0;
    __syncthreads();
    if (i < NEV) {
        float x = ev[i * 5 + 0];
        float y = ev[i * 5 + 1];
        float t = ev[i * 5 + 2];
        float p = ev[i * 5 + 3];
        int   b = (int)ev[i * 5 + 4];
        atomicMax(&smax[b & (BATCH - 1)], __float_as_int(t));
        int xi = min(max((int)x, 0), W_IN - 1);
        int row = (b * 2 + (int)p) * H_IN + (int)y;
        row = min(max(row, 0), NROW - 1);
        int pos = atomicAdd(&cursor[row * 16], 1);
        if (pos < CAP) {
            bucket[(size_t)row * CAP + pos] = make_float2(t, (float)xi);
        } else {
            int opos = atomicAdd(ovfc, 1);
            if (opos < OVF_CAP)
                ovf[opos] = make_float4(t, (float)xi, (float)row, 0.f);
        }
    }
    __syncthreads();
    if (tid < BATCH) atomicMax(&bmax_i[tid], smax[tid]);  // poison is negative -> ok
}

// ---------------- kernel C: fused accumulate + bilinear resize + bars ------
// Content block = (b, p, 8-output-row tile): zero 5x2160-float LDS, stage
// the 8 KB table in LDS, pull the 5 source rows' events from buckets
// (ds_add_f32), then interpolate all 9 bin-planes straight from LDS.
// Resize exploits scale == 3/8 exactly: each 8-px output group maps to 5
// input columns with a COMPILE-TIME weight/col pattern -> 10 LDS reads per
// (group, bin) for 8 outputs (was 32), y-lerp before x-lerp.
// Blocks 960..1247 write the constant-114 letterbox bars.
__global__ __launch_bounds__(256) void fused_kernel(const float2* __restrict__ bucket,
                               const int* __restrict__ cursor,
                               const int* __restrict__ bmax_i,
                               const float* __restrict__ table,
                               const float4* __restrict__ ovf,
                               const int* __restrict__ ovfc,
                               float* __restrict__ out) {
    __shared__ float sm[5 * ROWF];               // 43,200 B
    __shared__ float smt[TN + 1];                // 8,196 B (51.4 KB -> still 3 blk/CU)
    int blk = blockIdx.x;
    int tid = threadIdx.x;

    if (blk >= 960) {                            // letterbox bars
        const float4 v114 = make_float4(114.f, 114.f, 114.f, 114.f);
        float4* out4 = (float4*)out;
        int j0 = (blk - 960) * 12800 + tid;      // 288 blocks x 12800 float4
        for (int j = j0; j < (blk - 960 + 1) * 12800; j += 256) {
            int plane = j / 25600;
            int rem = j - plane * 25600;
            int row = rem / 160;
            int col = rem - row * 160;
            if (row >= 80) row += 480;           // 80..159 -> 560..639
            out4[((size_t)plane * IMG + row) * 160 + col] = v114;
        }
        return;
    }

    int b   = blk / 120;
    int rem = blk - b * 120;
    int p   = rem / 60;
    int yt  = rem - p * 60;
    int ry0 = yt * 8;                            // resized-content row of tile start
    float sy0 = fmaf((float)ry0 + 0.5f, 0.375f, -0.5f);
    int ybase = (int)floorf(sy0);                // == 3*yt - 1
    int rowbase = (b * 2 + p) * H_IN;
    float rbm = 1.0f / __int_as_float(bmax_i[b]);

    for (int c = tid; c < 5 * ROWF; c += 256) sm[c] = 0.f;
    for (int c = tid; c <= TN; c += 256) smt[c] = table[c];
    __syncthreads();

    // accumulate the 5 source rows this tile needs
    #pragma unroll
    for (int r = 0; r < 5; ++r) {
        int sr = min(max(ybase + r, 0), H_IN - 1);
        int row = rowbase + sr;
        int count = min(cursor[row * 16], CAP);
        for (int e = tid; e < count; e += 256) {
            float2 pay = bucket[(size_t)row * CAP + e];
            float tn = pay.x * rbm;
            int xi = (int)pay.y;
            float u0 = fmaf(tn, 1024.f, 1024.f);     // (tn+1)*TN/2
            int k0 = (int)floorf(u0);
            float f = u0 - (float)k0;
            #pragma unroll
            for (int bin = 0; bin < C_BINS; ++bin) {
                int k = k0 - 128 * bin;          // 128 = (1/8)*(TN/2), exact
                float fb = f;
                if (k >= TN) { k = TN - 1; fb = 1.f; }   // s == 1.0 (the max event)
                if (k < 0)   { k = 0;      fb = 0.f; }   // safety
                float t0 = smt[k], t1 = smt[k + 1];
                float g = fmaf(t1 - t0, fb, t0);
                atomicAdd(&sm[r * ROWF + xi * C_BINS + bin], tn * g);
            }
        }
    }
    // spill list (expected empty)
    int n = min(*ovfc, OVF_CAP);
    for (int j = tid; j < n; j += 256) {
        float4 pay = ovf[j];
        int orow = (int)pay.z;
        #pragma unroll
        for (int r = 0; r < 5; ++r) {
            int sr = min(max(ybase + r, 0), H_IN - 1);
            if (orow != rowbase + sr) continue;
            float tn = pay.x * rbm;
            int xi = (int)pay.y;
            float u0 = fmaf(tn, 1024.f, 1024.f);
            int k0 = (int)floorf(u0);
            float f = u0 - (float)k0;
            for (int bin = 0; bin < C_BINS; ++bin) {
                int k = k0 - 128 * bin;
                float fb = f;
                if (k >= TN) { k = TN - 1; fb = 1.f; }
                if (k < 0)   { k = 0;      fb = 0.f; }
                float t0 = smt[k], t1 = smt[k + 1];
                float g = fmaf(t1 - t0, fb, t0);
                atomicAdd(&sm[r * ROWF + xi * C_BINS + bin], tn * g);
            }
        }
    }
    __syncthreads();

    // bilinear resize straight out of LDS, 9 planes per block.
    // scale == 3/8: per 8-px group, constant wx pattern over 5 columns.
    int PB = b * 18 + p * 9;
    for (int item = tid; item < 640; item += 256) {      // 8 rows x 80 groups
        int row = item / 80;
        int grp = item - row * 80;
        int ry = ry0 + row;
        float sy = fmaf((float)ry + 0.5f, 0.375f, -0.5f);
        int y0 = (int)floorf(sy);
        float wy = sy - (float)y0;
        const float* r0 = sm + (max(y0, 0) - ybase) * ROWF;
        const float* r1 = sm + (min(y0 + 1, H_IN - 1) - ybase) * ROWF;
        int k3 = grp * 3;
        int cs0 = max(k3 - 1, 0) * C_BINS;               // clamp (grp==0 only)
        int cs1 = k3 * C_BINS;
        int cs2 = cs1 + C_BINS;
        int cs3 = cs2 + C_BINS;
        int cs4 = min(k3 + 3, W_IN - 1) * C_BINS;        // clamp (grp==79 only)
        int oy = 80 + ry;
        #pragma unroll
        for (int bin = 0; bin < C_BINS; ++bin) {
            float a0 = r0[cs0 + bin], a1 = r0[cs1 + bin], a2 = r0[cs2 + bin],
                  a3 = r0[cs3 + bin], a4 = r0[cs4 + bin];
            float b0 = r1[cs0 + bin], b1v = r1[cs1 + bin], b2v = r1[cs2 + bin],
                  b3v = r1[cs3 + bin], b4 = r1[cs4 + bin];
            float v0 = fmaf(b0 - a0, wy, a0);
            float v1 = fmaf(b1v - a1, wy, a1);
            float v2 = fmaf(b2v - a2, wy, a2);
            float v3 = fmaf(b3v - a3, wy, a3);
            float v4 = fmaf(b4 - a4, wy, a4);
            float o0 = fmaf(v1 - v0, 0.6875f, v0);
            float o1 = fmaf(v2 - v1, 0.0625f, v1);
            float o2 = fmaf(v2 - v1, 0.4375f, v1);
            float o3 = fmaf(v2 - v1, 0.8125f, v1);
            float o4 = fmaf(v3 - v2, 0.1875f, v2);
            float o5 = fmaf(v3 - v2, 0.5625f, v2);
            float o6 = fmaf(v3 - v2, 0.9375f, v2);
            float o7 = fmaf(v4 - v3, 0.3125f, v3);
            float4* d = (float4*)(out + ((size_t)(PB + bin) * IMG + oy) * IMG) + grp * 2;
            d[0] = make_float4(o0, o1, o2, o3);
            d[1] = make_float4(o4, o5, o6, o7);
        }
    }
}

extern "C" void kernel_launch(void* const* d_in, const int* in_sizes, int n_in,
                              void* d_out, int out_size, void* d_ws, size_t ws_size,
                              hipStream_t stream) {
    const float* ev = (const float*)d_in[0];
    const float* W1 = (const float*)d_in[1];
    const float* b1 = (const float*)d_in[2];
    const float* W2 = (const float*)d_in[3];
    const float* b2 = (const float*)d_in[4];
    const float* W3 = (const float*)d_in[5];
    const float* b3 = (const float*)d_in[6];
    float* out = (float*)d_out;

    char* ws = (char*)d_ws;
    int*    bmax_i = (int*)(ws + WS_BMAX_OFF);
    int*    ovfc   = (int*)(ws + WS_OVFC_OFF);
    float*  table  = (float*)(ws + WS_TABLE_OFF);
    int*    cursor = (int*)(ws + WS_CUR_OFF);
    float2* bucket = (float2*)(ws + WS_BKT_OFF);
    float4* ovf    = (float4*)(ws + WS_OVF_OFF);

    prep_kernel<<<TN + 1, 128, 0, stream>>>(W1, b1, W2, b2, W3, b3,
                                            table, cursor, ovfc);
    place_kernel<<<(NEV + 255) / 256, 256, 0, stream>>>(ev, cursor, bucket,
                                                        bmax_i, ovfc, ovf);
    fused_kernel<<<960 + 288, 256, 0, stream>>>(bucket, cursor, bmax_i, table,
                                                ovf, ovfc, out);
}

// Round 6
// 307.387 us; speedup vs baseline: 1.0578x; 1.0578x over previous
//
#include <hip/hip_runtime.h>

// Problem constants (match reference)
#define C_BINS 9
#define H_IN 180
#define W_IN 240
#define IMG 640
#define NEV 250000
#define BATCH 8
#define NEG_SLOPE 0.1f
#define HW (H_IN * W_IN)                         // 43200
#define TN 2048                                  // table intervals (TN+1 nodes over [-1,1])
#define ROWF (W_IN * C_BINS)                     // 2160 floats per accumulated row
#define NROW (2 * BATCH * H_IN)                  // 2880 (b,p,y) rows
#define CAP 512                                  // bucket capacity per row (mean 87)
#define OVF_CAP 4096                             // spill list capacity (expected count: 0)

// workspace layout (bytes)
#define WS_BMAX_OFF   0            // 8 x i32 (float bits; signed-max trick, no init needed)
#define WS_OVFC_OFF   64           // 1 x i32 spill cursor
#define WS_TABLE_OFF  128          // (TN+1) x f32 -> ends 8324
#define WS_CUR_OFF    16384        // NROW x i32, padded x16 (one counter per 64B line)
#define WS_BKT_OFF    262144       // NROW x CAP x float2 = 11.8 MB
#define WS_OVF_OFF    12582912     // OVF_CAP x float4 = 64 KB

// ---------------- kernel A: prep (table + cursor zero) --------------------
__global__ __launch_bounds__(128) void prep_kernel(
        const float* __restrict__ W1, const float* __restrict__ b1,
        const float* __restrict__ W2, const float* __restrict__ b2,
        const float* __restrict__ W3, const float* __restrict__ b3,
        float* __restrict__ table, int* __restrict__ cursor,
        int* __restrict__ ovfc) {
    int blk = blockIdx.x, tid = threadIdx.x;
    int gtid = blk * 128 + tid;
    int gstride = gridDim.x * 128;
    for (int i = gtid; i < NROW * 16; i += gstride) cursor[i] = 0;
    if (gtid == 0) *ovfc = 0;

    // table node `blk`: two LeakyReLU layers + final linear, at s = -1 + 2*blk/TN
    __shared__ float h1s[100];
    __shared__ float red[128];
    float s = -1.f + 2.f * (float)blk / (float)TN;
    if (tid < 100) {
        float h = fmaf(s, W1[tid], b1[tid]);
        h1s[tid] = h > 0.f ? h : NEG_SLOPE * h;
    }
    __syncthreads();
    float acc = 0.f;
    if (tid < 100) {
        #pragma unroll 4
        for (int j = 0; j < 100; ++j) acc = fmaf(h1s[j], W2[j * 100 + tid], acc);
        acc += b2[tid];
        acc = acc > 0.f ? acc : NEG_SLOPE * acc;
        acc *= W3[tid];
    }
    red[tid] = tid < 100 ? acc : 0.f;
    __syncthreads();
    for (int off = 64; off > 0; off >>= 1) {
        if (tid < off) red[tid] += red[tid + off];
        __syncthreads();
    }
    if (tid == 0) table[blk] = red[0] + b3[0];
}

// ---------------- kernel B: place events into row buckets + batch max ------
__global__ __launch_bounds__(256) void place_kernel(const float* __restrict__ ev,
                               int* __restrict__ cursor,
                               float2* __restrict__ bucket,
                               int* __restrict__ bmax_i,
                               int* __restrict__ ovfc,
                               float4* __restrict__ ovf) {
    int i = blockIdx.x * 256 + threadIdx.x;
    int tid = threadIdx.x;
    __shared__ int smax[BATCH];
    if (tid < BATCH) smax[tid] = 0;
    __syncthreads();
    if (i < NEV) {
        float x = ev[i * 5 + 0];
        float y = ev[i * 5 + 1];
        float t = ev[i * 5 + 2];
        float p = ev[i * 5 + 3];
        int   b = (int)ev[i * 5 + 4];
        atomicMax(&smax[b & (BATCH - 1)], __float_as_int(t));
        int xi = min(max((int)x, 0), W_IN - 1);
        int row = (b * 2 + (int)p) * H_IN + (int)y;
        row = min(max(row, 0), NROW - 1);
        int pos = atomicAdd(&cursor[row * 16], 1);
        if (pos < CAP) {
            bucket[(size_t)row * CAP + pos] = make_float2(t, (float)xi);
        } else {
            int opos = atomicAdd(ovfc, 1);
            if (opos < OVF_CAP)
                ovf[opos] = make_float4(t, (float)xi, (float)row, 0.f);
        }
    }
    __syncthreads();
    if (tid < BATCH) atomicMax(&bmax_i[tid], smax[tid]);  // poison is negative -> ok
}

// ---------------- kernel C: fused accumulate + bilinear resize + bars ------
// BISECT vs round 5: resize loop restored to the round-3 known-good version
// (res[9][4], small live windows); smt table staging and the reciprocal
// hoist are KEPT. Single-variable test of the resize-rewrite-spill theory.
__global__ __launch_bounds__(256) void fused_kernel(const float2* __restrict__ bucket,
                               const int* __restrict__ cursor,
                               const int* __restrict__ bmax_i,
                               const float* __restrict__ table,
                               const float4* __restrict__ ovf,
                               const int* __restrict__ ovfc,
                               float* __restrict__ out) {
    __shared__ float sm[5 * ROWF];               // 43,200 B
    __shared__ float smt[TN + 1];                // 8,196 B (51.4 KB -> still 3 blk/CU)
    int blk = blockIdx.x;
    int tid = threadIdx.x;

    if (blk >= 960) {                            // letterbox bars
        const float4 v114 = make_float4(114.f, 114.f, 114.f, 114.f);
        float4* out4 = (float4*)out;
        int j0 = (blk - 960) * 12800 + tid;      // 288 blocks x 12800 float4
        for (int j = j0; j < (blk - 960 + 1) * 12800; j += 256) {
            int plane = j / 25600;
            int rem = j - plane * 25600;
            int row = rem / 160;
            int col = rem - row * 160;
            if (row >= 80) row += 480;           // 80..159 -> 560..639
            out4[((size_t)plane * IMG + row) * 160 + col] = v114;
        }
        return;
    }

    int b   = blk / 120;
    int rem = blk - b * 120;
    int p   = rem / 60;
    int yt  = rem - p * 60;
    int ry0 = yt * 8;                            // resized-content row of tile start
    float sy0 = fmaf((float)ry0 + 0.5f, 0.375f, -0.5f);
    int ybase = (int)floorf(sy0);                // == 3*yt - 1
    int rowbase = (b * 2 + p) * H_IN;
    float rbm = 1.0f / __int_as_float(bmax_i[b]);

    for (int c = tid; c < 5 * ROWF; c += 256) sm[c] = 0.f;
    for (int c = tid; c <= TN; c += 256) smt[c] = table[c];
    __syncthreads();

    // accumulate the 5 source rows this tile needs
    #pragma unroll
    for (int r = 0; r < 5; ++r) {
        int sr = min(max(ybase + r, 0), H_IN - 1);
        int row = rowbase + sr;
        int count = min(cursor[row * 16], CAP);
        for (int e = tid; e < count; e += 256) {
            float2 pay = bucket[(size_t)row * CAP + e];
            float tn = pay.x * rbm;
            int xi = (int)pay.y;
            float u0 = fmaf(tn, 1024.f, 1024.f);     // (tn+1)*TN/2
            int k0 = (int)floorf(u0);
            float f = u0 - (float)k0;
            #pragma unroll
            for (int bin = 0; bin < C_BINS; ++bin) {
                int k = k0 - 128 * bin;          // 128 = (1/8)*(TN/2), exact
                float fb = f;
                if (k >= TN) { k = TN - 1; fb = 1.f; }   // s == 1.0 (the max event)
                if (k < 0)   { k = 0;      fb = 0.f; }   // safety
                float t0 = smt[k], t1 = smt[k + 1];
                float g = fmaf(t1 - t0, fb, t0);
                atomicAdd(&sm[r * ROWF + xi * C_BINS + bin], tn * g);
            }
        }
    }
    // spill list (expected empty)
    int n = min(*ovfc, OVF_CAP);
    for (int j = tid; j < n; j += 256) {
        float4 pay = ovf[j];
        int orow = (int)pay.z;
        #pragma unroll
        for (int r = 0; r < 5; ++r) {
            int sr = min(max(ybase + r, 0), H_IN - 1);
            if (orow != rowbase + sr) continue;
            float tn = pay.x * rbm;
            int xi = (int)pay.y;
            float u0 = fmaf(tn, 1024.f, 1024.f);
            int k0 = (int)floorf(u0);
            float f = u0 - (float)k0;
            for (int bin = 0; bin < C_BINS; ++bin) {
                int k = k0 - 128 * bin;
                float fb = f;
                if (k >= TN) { k = TN - 1; fb = 1.f; }
                if (k < 0)   { k = 0;      fb = 0.f; }
                float t0 = smt[k], t1 = smt[k + 1];
                float g = fmaf(t1 - t0, fb, t0);
                atomicAdd(&sm[r * ROWF + xi * C_BINS + bin], tn * g);
            }
        }
    }
    __syncthreads();

    // bilinear resize straight out of LDS, 9 planes per block (round-3 version)
    int PB = b * 18 + p * 9;
    for (int g = tid; g < 1280; g += 256) {
        int row = g / 160;
        int gx = g - row * 160;
        int ry = ry0 + row;
        float sy = fmaf((float)ry + 0.5f, 0.375f, -0.5f);
        int y0 = (int)floorf(sy);
        float wy = sy - (float)y0;
        const float* r0 = sm + (max(y0, 0) - ybase) * ROWF;
        const float* r1 = sm + (min(y0 + 1, H_IN - 1) - ybase) * ROWF;
        float res[C_BINS][4];
        #pragma unroll
        for (int q = 0; q < 4; ++q) {
            int ox = gx * 4 + q;
            float sx = fmaf((float)ox + 0.5f, 0.375f, -0.5f);
            int x0 = (int)floorf(sx);
            float wx = sx - (float)x0;
            int x1 = min(x0 + 1, W_IN - 1);
            x0 = max(x0, 0);
            int o0 = x0 * C_BINS, o1 = x1 * C_BINS;
            #pragma unroll
            for (int bin = 0; bin < C_BINS; ++bin) {
                float v00 = r0[o0 + bin], v01 = r0[o1 + bin];
                float v10 = r1[o0 + bin], v11 = r1[o1 + bin];
                float top = fmaf(v01 - v00, wx, v00);
                float bot = fmaf(v11 - v10, wx, v10);
                res[bin][q] = fmaf(bot - top, wy, top);
            }
        }
        int oy = 80 + ry;
        #pragma unroll
        for (int bin = 0; bin < C_BINS; ++bin) {
            float4* dst = (float4*)(out + ((size_t)(PB + bin) * IMG + oy) * IMG);
            dst[gx] = make_float4(res[bin][0], res[bin][1], res[bin][2], res[bin][3]);
        }
    }
}

extern "C" void kernel_launch(void* const* d_in, const int* in_sizes, int n_in,
                              void* d_out, int out_size, void* d_ws, size_t ws_size,
                              hipStream_t stream) {
    const float* ev = (const float*)d_in[0];
    const float* W1 = (const float*)d_in[1];
    const float* b1 = (const float*)d_in[2];
    const float* W2 = (const float*)d_in[3];
    const float* b2 = (const float*)d_in[4];
    const float* W3 = (const float*)d_in[5];
    const float* b3 = (const float*)d_in[6];
    float* out = (float*)d_out;

    char* ws = (char*)d_ws;
    int*    bmax_i = (int*)(ws + WS_BMAX_OFF);
    int*    ovfc   = (int*)(ws + WS_OVFC_OFF);
    float*  table  = (float*)(ws + WS_TABLE_OFF);
    int*    cursor = (int*)(ws + WS_CUR_OFF);
    float2* bucket = (float2*)(ws + WS_BKT_OFF);
    float4* ovf    = (float4*)(ws + WS_OVF_OFF);

    prep_kernel<<<TN + 1, 128, 0, stream>>>(W1, b1, W2, b2, W3, b3,
                                            table, cursor, ovfc);
    place_kernel<<<(NEV + 255) / 256, 256, 0, stream>>>(ev, cursor, bucket,
                                                        bmax_i, ovfc, ovf);
    fused_kernel<<<960 + 288, 256, 0, stream>>>(bucket, cursor, bmax_i, table,
                                                ovf, ovfc, out);
}

// Round 7
// 301.041 us; speedup vs baseline: 1.0801x; 1.0211x over previous
//
#include <hip/hip_runtime.h>

// Problem constants (match reference)
#define C_BINS 9
#define H_IN 180
#define W_IN 240
#define IMG 640
#define NEV 250000
#define BATCH 8
#define NEG_SLOPE 0.1f
#define HW (H_IN * W_IN)                         // 43200
#define TN 2048                                  // table intervals (TN+1 nodes over [-1,1])
#define ROWF (W_IN * C_BINS)                     // 2160 floats per accumulated row
#define NROW (2 * BATCH * H_IN)                  // 2880 (b,p,y) rows
#define CAP 512                                  // bucket capacity per row (mean 87)
#define OVF_CAP 4096                             // spill list capacity (expected count: 0)
#define PLACE_NB ((NEV + 255) / 256)             // 977 blocks

// workspace layout (bytes)
#define WS_BMAX_OFF   0            // 8 x i32 (zeroed by memset; any positive wins)
#define WS_OVFC_OFF   64           // 1 x i32 spill cursor (zeroed by memset)
#define WS_TABLE_OFF  128          // (TN+1) x f32 -> ends 8324
#define WS_CUR_OFF    16384        // NROW x i32, padded x16 (one counter per 64B line)
#define WS_ZERO_BYTES 262144       // one memset covers bmax/ovfc/table/cursors
#define WS_BKT_OFF    262144       // NROW x CAP x float2 = 11.8 MB
#define WS_OVF_OFF    12582912     // OVF_CAP x float4 = 64 KB

// ---------------- kernel A: place events into row buckets + bmax + table --
// One cursor atomic per event (2880 line-padded counters). Payload = (t, x);
// b,p,y implied by row. bmax fused (reuses the event read). The value-table
// (consumed only by the fused kernel, no dependency on cursors/events) is
// computed in this kernel's tail: block blk handles nodes blk, blk+977, ...
// (structure measured launch-neutral in R4-vs-R5 A/B).
__global__ __launch_bounds__(256) void place_kernel(const float* __restrict__ ev,
                               const float* __restrict__ W1, const float* __restrict__ b1,
                               const float* __restrict__ W2, const float* __restrict__ b2,
                               const float* __restrict__ W3, const float* __restrict__ b3,
                               int* __restrict__ cursor,
                               float2* __restrict__ bucket,
                               int* __restrict__ bmax_i,
                               int* __restrict__ ovfc,
                               float4* __restrict__ ovf,
                               float* __restrict__ table) {
    int i = blockIdx.x * 256 + threadIdx.x;
    int tid = threadIdx.x;
    __shared__ int smax[BATCH];
    __shared__ float h1s[100];
    __shared__ float red[256];
    if (tid < BATCH) smax[tid] = 0;
    __syncthreads();
    if (i < NEV) {
        float x = ev[i * 5 + 0];
        float y = ev[i * 5 + 1];
        float t = ev[i * 5 + 2];
        float p = ev[i * 5 + 3];
        int   b = (int)ev[i * 5 + 4];
        atomicMax(&smax[b & (BATCH - 1)], __float_as_int(t));
        int xi = min(max((int)x, 0), W_IN - 1);
        int row = (b * 2 + (int)p) * H_IN + (int)y;
        row = min(max(row, 0), NROW - 1);
        int pos = atomicAdd(&cursor[row * 16], 1);
        if (pos < CAP) {
            bucket[(size_t)row * CAP + pos] = make_float2(t, (float)xi);
        } else {
            int opos = atomicAdd(ovfc, 1);
            if (opos < OVF_CAP)
                ovf[opos] = make_float4(t, (float)xi, (float)row, 0.f);
        }
    }
    __syncthreads();
    if (tid < BATCH) atomicMax(&bmax_i[tid], smax[tid]);  // zeroed -> any positive wins

    // table nodes: two LeakyReLU layers + final linear at s = -1 + 2*node/TN
    for (int node = blockIdx.x; node <= TN; node += PLACE_NB) {
        float s = -1.f + 2.f * (float)node / (float)TN;
        if (tid < 100) {
            float h = fmaf(s, W1[tid], b1[tid]);
            h1s[tid] = h > 0.f ? h : NEG_SLOPE * h;
        }
        __syncthreads();
        float acc = 0.f;
        if (tid < 100) {
            #pragma unroll 4
            for (int j = 0; j < 100; ++j) acc = fmaf(h1s[j], W2[j * 100 + tid], acc);
            acc += b2[tid];
            acc = acc > 0.f ? acc : NEG_SLOPE * acc;
            acc *= W3[tid];
        }
        red[tid] = tid < 100 ? acc : 0.f;
        __syncthreads();
        for (int off = 128; off > 0; off >>= 1) {
            if (tid < off) red[tid] += red[tid + off];
            __syncthreads();
        }
        if (tid == 0) table[node] = red[0] + b3[0];
    }
}

// ---------------- kernel B: fused accumulate + bilinear resize + bars ------
// EXACT round-3 fused kernel (best measured: 300.8 total). Content block =
// (b, p, 8-output-row tile): zero 5x2160-float LDS, pull the 5 source rows'
// events from buckets (ds_add_f32), interpolate all 9 bin-planes from LDS.
// Blocks 960..1247 write the constant-114 letterbox bars.
__global__ __launch_bounds__(256) void fused_kernel(const float2* __restrict__ bucket,
                               const int* __restrict__ cursor,
                               const int* __restrict__ bmax_i,
                               const float* __restrict__ table,
                               const float4* __restrict__ ovf,
                               const int* __restrict__ ovfc,
                               float* __restrict__ out) {
    __shared__ float sm[5 * ROWF];               // 43,200 B -> 3 blocks/CU
    int blk = blockIdx.x;
    int tid = threadIdx.x;

    if (blk >= 960) {                            // letterbox bars
        const float4 v114 = make_float4(114.f, 114.f, 114.f, 114.f);
        float4* out4 = (float4*)out;
        int j0 = (blk - 960) * 12800 + tid;      // 288 blocks x 12800 float4
        for (int j = j0; j < (blk - 960 + 1) * 12800; j += 256) {
            int plane = j / 25600;
            int rem = j - plane * 25600;
            int row = rem / 160;
            int col = rem - row * 160;
            if (row >= 80) row += 480;           // 80..159 -> 560..639
            out4[((size_t)plane * IMG + row) * 160 + col] = v114;
        }
        return;
    }

    int b   = blk / 120;
    int rem = blk - b * 120;
    int p   = rem / 60;
    int yt  = rem - p * 60;
    int ry0 = yt * 8;                            // resized-content row of tile start
    float sy0 = fmaf((float)ry0 + 0.5f, 0.375f, -0.5f);
    int ybase = (int)floorf(sy0);
    int rowbase = (b * 2 + p) * H_IN;
    float bm = __int_as_float(bmax_i[b]);

    for (int c = tid; c < 5 * ROWF; c += 256) sm[c] = 0.f;
    __syncthreads();

    // accumulate the 5 source rows this tile needs
    #pragma unroll
    for (int r = 0; r < 5; ++r) {
        int sr = min(max(ybase + r, 0), H_IN - 1);
        int row = rowbase + sr;
        int count = min(cursor[row * 16], CAP);
        for (int e = tid; e < count; e += 256) {
            float2 pay = bucket[(size_t)row * CAP + e];
            float tn = pay.x / bm;
            int xi = (int)pay.y;
            float u0 = (tn + 1.f) * (0.5f * (float)TN);
            int k0 = (int)floorf(u0);
            float f = u0 - (float)k0;
            #pragma unroll
            for (int bin = 0; bin < C_BINS; ++bin) {
                int k = k0 - 128 * bin;          // 128 = (1/8)*(TN/2), exact
                float fb = f;
                if (k >= TN) { k = TN - 1; fb = 1.f; }   // s == 1.0 (the max event)
                if (k < 0)   { k = 0;      fb = 0.f; }   // safety
                float t0 = table[k], t1 = table[k + 1];
                float g = fmaf(t1 - t0, fb, t0);
                atomicAdd(&sm[r * ROWF + xi * C_BINS + bin], tn * g);
            }
        }
    }
    // spill list (expected empty)
    int n = min(*ovfc, OVF_CAP);
    for (int j = tid; j < n; j += 256) {
        float4 pay = ovf[j];
        int orow = (int)pay.z;
        #pragma unroll
        for (int r = 0; r < 5; ++r) {
            int sr = min(max(ybase + r, 0), H_IN - 1);
            if (orow != rowbase + sr) continue;
            float tn = pay.x / bm;
            int xi = (int)pay.y;
            float u0 = (tn + 1.f) * (0.5f * (float)TN);
            int k0 = (int)floorf(u0);
            float f = u0 - (float)k0;
            for (int bin = 0; bin < C_BINS; ++bin) {
                int k = k0 - 128 * bin;
                float fb = f;
                if (k >= TN) { k = TN - 1; fb = 1.f; }
                if (k < 0)   { k = 0;      fb = 0.f; }
                float t0 = table[k], t1 = table[k + 1];
                float g = fmaf(t1 - t0, fb, t0);
                atomicAdd(&sm[r * ROWF + xi * C_BINS + bin], tn * g);
            }
        }
    }
    __syncthreads();

    // bilinear resize straight out of LDS, 9 planes per block
    int PB = b * 18 + p * 9;
    for (int g = tid; g < 1280; g += 256) {
        int row = g / 160;
        int gx = g - row * 160;
        int ry = ry0 + row;
        float sy = fmaf((float)ry + 0.5f, 0.375f, -0.5f);
        int y0 = (int)floorf(sy);
        float wy = sy - (float)y0;
        const float* r0 = sm + (max(y0, 0) - ybase) * ROWF;
        const float* r1 = sm + (min(y0 + 1, H_IN - 1) - ybase) * ROWF;
        float res[C_BINS][4];
        #pragma unroll
        for (int q = 0; q < 4; ++q) {
            int ox = gx * 4 + q;
            float sx = fmaf((float)ox + 0.5f, 0.375f, -0.5f);
            int x0 = (int)floorf(sx);
            float wx = sx - (float)x0;
            int x1 = min(x0 + 1, W_IN - 1);
            x0 = max(x0, 0);
            int o0 = x0 * C_BINS, o1 = x1 * C_BINS;
            #pragma unroll
            for (int bin = 0; bin < C_BINS; ++bin) {
                float v00 = r0[o0 + bin], v01 = r0[o1 + bin];
                float v10 = r1[o0 + bin], v11 = r1[o1 + bin];
                float top = fmaf(v01 - v00, wx, v00);
                float bot = fmaf(v11 - v10, wx, v10);
                res[bin][q] = fmaf(bot - top, wy, top);
            }
        }
        int oy = 80 + ry;
        #pragma unroll
        for (int bin = 0; bin < C_BINS; ++bin) {
            float4* dst = (float4*)(out + ((size_t)(PB + bin) * IMG + oy) * IMG);
            dst[gx] = make_float4(res[bin][0], res[bin][1], res[bin][2], res[bin][3]);
        }
    }
}

extern "C" void kernel_launch(void* const* d_in, const int* in_sizes, int n_in,
                              void* d_out, int out_size, void* d_ws, size_t ws_size,
                              hipStream_t stream) {
    const float* ev = (const float*)d_in[0];
    const float* W1 = (const float*)d_in[1];
    const float* b1 = (const float*)d_in[2];
    const float* W2 = (const float*)d_in[3];
    const float* b2 = (const float*)d_in[4];
    const float* W3 = (const float*)d_in[5];
    const float* b3 = (const float*)d_in[6];
    float* out = (float*)d_out;

    char* ws = (char*)d_ws;
    int*    bmax_i = (int*)(ws + WS_BMAX_OFF);
    int*    ovfc   = (int*)(ws + WS_OVFC_OFF);
    float*  table  = (float*)(ws + WS_TABLE_OFF);
    int*    cursor = (int*)(ws + WS_CUR_OFF);
    float2* bucket = (float2*)(ws + WS_BKT_OFF);
    float4* ovf    = (float4*)(ws + WS_OVF_OFF);

    // DMA-zero bmax/ovfc/table-region/cursors (256 KB) -- replaces the prep
    // kernel; graph-capturable stream op (the harness itself uses it).
    hipMemsetAsync(ws, 0, WS_ZERO_BYTES, stream);
    place_kernel<<<PLACE_NB, 256, 0, stream>>>(ev, W1, b1, W2, b2, W3, b3,
                                               cursor, bucket, bmax_i, ovfc, ovf,
                                               table);
    fused_kernel<<<960 + 288, 256, 0, stream>>>(bucket, cursor, bmax_i, table,
                                                ovf, ovfc, out);
}